// Round 6
// baseline (1313.803 us; speedup 1.0000x reference)
//
#include <hip/hip_runtime.h>
#include <hip/hip_bf16.h>

// MeshConvNet on MI355X (gfx950) — round 12: revert bf16-h (absmax 20>19.6), keep B-prefetch.
// r11 postmortem: bf16 h storage re-rounds per layer x4 — compounds to absmax 20, just
// over. The B-prefetch half is math-neutral (same values, loaded earlier). This round:
// fp32 h via the ws_size-gated dispatch (as r6-r10), B-prefetch ping-pong kept.
// -> absmax should return to EXACTLY 12.0 (bit-identical math to r10).
// Lever under test: B frags prefetched one chunk ahead (static bqA/bqB, 2x-unrolled
// loop) removes the ~300cyc/chunk exposed vmcnt wait r10 had (Mfma 22, latency-bound).
// VGPR ~84+32acc <= 128 -> still 2 blocks/CU. Tripwire: WRITE_SIZE ~66MB (spills).

#define B_ 4
#define E_ 16384

typedef short short8 __attribute__((ext_vector_type(8)));
typedef float floatx4 __attribute__((ext_vector_type(4)));

__device__ __forceinline__ float lk(float v) { return v > 0.0f ? v : 0.01f * v; }
__device__ __forceinline__ float b2f(__hip_bfloat16 h) { return __bfloat162float(h); }
__device__ __forceinline__ __hip_bfloat16 f2b(float f) { return __float2bfloat16(f); }

// Barrier that only waits on LDS (lgkmcnt), not in-flight global loads (vmcnt).
__device__ __forceinline__ void barrier_lds() {
    __builtin_amdgcn_fence(__ATOMIC_RELEASE, "workgroup", "local");
    __builtin_amdgcn_s_barrier();
    __builtin_amdgcn_fence(__ATOMIC_ACQUIRE, "workgroup", "local");
}

template <typename TS>
struct Cvt;
template <>
struct Cvt<float> {
    static __device__ __forceinline__ float to(float f) { return f; }
    static __device__ __forceinline__ float from(float s) { return s; }
    static __device__ __forceinline__ float ld1(const float* p) { return *p; }
};
template <>
struct Cvt<__hip_bfloat16> {
    static __device__ __forceinline__ __hip_bfloat16 to(float f) { return f2b(f); }
    static __device__ __forceinline__ float from(__hip_bfloat16 s) { return b2f(s); }
    static __device__ __forceinline__ float ld1(const __hip_bfloat16* p) { return b2f(*p); }
};

// ---------------- x [B][128][E] fp32 -> xT [B*E][128] TS ----------------
template <typename TS>
__global__ void k_transpose_x(const float* __restrict__ x, TS* __restrict__ xT) {
    __shared__ float t[32][33];
    const int b = blockIdx.z, c0 = blockIdx.y * 32, e0 = blockIdx.x * 32;
    const int tx = threadIdx.x & 31, ty = threadIdx.x >> 5;
#pragma unroll
    for (int i = 0; i < 4; ++i) {
        const int c = ty + i * 8;
        t[c][tx] = x[((size_t)b * 128 + c0 + c) * E_ + e0 + tx];
    }
    __syncthreads();
#pragma unroll
    for (int i = 0; i < 4; ++i) {
        const int e = ty + i * 8;
        xT[((size_t)b * E_ + e0 + e) * 128 + c0 + tx] = Cvt<TS>::to(t[tx][e]);
    }
}

// ---- W [256][C][7] fp32 -> wf2 in MFMA-fragment order, bf16 hi only ----
// Layout: t = ((ci*4 + w4)*4 + nt)*2 + ks -> 64 lanes x 8 shorts (16B/lane, 1KB/wave).
// Lane (qd*16+l15) holds B[o = w4*64+nt*16+l15][k-in-chunk = (c&7)*8+f], where
// c = ci*8 + ks*4 + qd and f==7 zero-padded.
__global__ void k_prep_w(const float* __restrict__ w, __hip_bfloat16* __restrict__ wf2, int C) {
    const int NCH = C / 8;
    const int idx = blockIdx.x * blockDim.x + threadIdx.x;
    const int lane = idx & 63, t = idx >> 6;
    const int ks = t & 1, nt = (t >> 1) & 3, w4 = (t >> 3) & 3, ci = t >> 5;
    if (ci >= NCH) return;
    const int o = w4 * 64 + nt * 16 + (lane & 15);
    const int c = ci * 8 + ks * 4 + (lane >> 4);
    const float* src = w + ((size_t)o * C + c) * 7;
    __hip_bfloat16* dst = wf2 + (size_t)idx * 8;
#pragma unroll
    for (int f = 0; f < 7; ++f) dst[f] = f2b(src[f]);
    dst[7] = f2b(0.0f);
}

// ---------------- per-channel sum & sumsq of leaky(h), h [B*E][256] ----------------
template <typename TS>
__global__ void k_bn_stats(const TS* __restrict__ h, float* __restrict__ stats) {
    const int c = threadIdx.x;
    const size_t r0 = (size_t)blockIdx.x * 64;  // 1024 blocks x 64 rows
    float s = 0.0f, q = 0.0f;
    for (int r = 0; r < 64; ++r) {
        const float v = lk(Cvt<TS>::from(h[(r0 + r) * 256 + c]));
        s += v;
        q += v * v;
    }
    atomicAdd(&stats[c], s);
    atomicAdd(&stats[256 + c], q);
}

__global__ void k_bn_finalize(const float* __restrict__ stats, const float* __restrict__ gamma,
                              const float* __restrict__ beta, float* __restrict__ scale,
                              float* __restrict__ bias) {
    const int c = threadIdx.x;
    const float n = 1.0f / 65536.0f;
    const float mean = stats[c] * n;
    const float var = stats[256 + c] * n - mean * mean;
    const float inv = rsqrtf(var + 1e-5f);
    const float s = gamma[c] * inv;
    scale[c] = s;
    bias[c] = beta[c] - mean * s;
}

// ---------------- fused gather + features + bf16 MFMA GEMM ----------------
// 512 thr = 8 waves, tile 64 edges x 256 outs, chunk = 8 channels (k=64, A = bf16).
// Thread = edge (tid>>3) x channel (tid&7). A double-buffered in LDS; B fragments
// prefetched one chunk ahead into static bqA/bqB (2x-unrolled loop). One barrier/chunk.
// Wave tile 32x64: acc[2][4] = 32 AGPR -> 2 blocks/CU at launch_bounds(512,4).
template <int C, bool BN, typename TS>
__global__ __launch_bounds__(512, 4) void k_conv(const TS* __restrict__ hin,
                                                 const int* __restrict__ edges,
                                                 const __hip_bfloat16* __restrict__ wf2,
                                                 const float* __restrict__ scale,
                                                 const float* __restrict__ bias,
                                                 TS* __restrict__ hout) {
    constexpr int NCH = C / 8;  // chunks (16 or 32, always even)
    constexpr int ASA = 72;     // A row stride in shorts: [hi 64 | pad 8]
    __shared__ __align__(16) __hip_bfloat16 Asm[2][64 * ASA];  // 2 x 9216 B
    __shared__ float ssc[256];
    __shared__ float ssb[256];

    const int tid = threadIdx.x;
    const int tm = blockIdx.x;  // 1024 m-tiles (256 per batch)
    const int b = tm >> 8;
    const int e0 = (tm & 255) * 64;
    const int wave = tid >> 6, lane = tid & 63;

    if constexpr (BN) {
        if (tid < C) {
            ssc[tid] = scale[tid];
            ssb[tid] = bias[tid];
        }
    }

    // ---- gather assignment: every thread owns (edge, 1 channel)
    const int e_loc = tid >> 3;  // 0..63
    const int ch = tid & 7;      // channel within 8-ch chunk
    const TS* rp0;
    const TS* rp1;
    const TS* rp2;
    const TS* rp3;
    const TS* rp4;
    {
        const int4 nb =
            *reinterpret_cast<const int4*>(edges + (((size_t)b * E_) + e0 + e_loc) * 4);
        const size_t rb = (size_t)b * E_;
        rp0 = hin + (rb + e0 + e_loc) * C + ch;
        rp1 = hin + (rb + nb.x) * C + ch;
        rp2 = hin + (rb + nb.y) * C + ch;
        rp3 = hin + (rb + nb.z) * C + ch;
        rp4 = hin + (rb + nb.w) * C + ch;
    }

    floatx4 acc[2][4];
#pragma unroll
    for (int i = 0; i < 2; ++i)
#pragma unroll
        for (int j = 0; j < 4; ++j) {
            floatx4 z = {0.0f, 0.0f, 0.0f, 0.0f};
            acc[i][j] = z;
        }

    const int wm = (wave & 1) * 32;
    const int w4 = wave >> 1;  // 0..3: 64-col n-tile
    const int wn = w4 * 64;
    const int qd = lane >> 4, l15 = lane & 15;

    float pf[5];
    auto issue_gathers = [&](int cch) {
        const int co = cch * 8;
        pf[0] = Cvt<TS>::ld1(rp0 + co);
        pf[1] = Cvt<TS>::ld1(rp1 + co);
        pf[2] = Cvt<TS>::ld1(rp2 + co);
        pf[3] = Cvt<TS>::ld1(rp3 + co);
        pf[4] = Cvt<TS>::ld1(rp4 + co);
    };
    // pf must hold chunk cch's data; writes features into Asm[bs]
    auto produce = [&](int cch, int bs) {
        float f0 = pf[0], f1 = pf[1], f2 = pf[2], f3 = pf[3], f4 = pf[4];
        if constexpr (BN) {
            const float sA = ssc[cch * 8 + ch];
            const float bA = ssb[cch * 8 + ch];
            f0 = lk(f0) * sA + bA;
            f1 = lk(f1) * sA + bA;
            f2 = lk(f2) * sA + bA;
            f3 = lk(f3) * sA + bA;
            f4 = lk(f4) * sA + bA;
        }
        float gf[8];
        gf[0] = f0;
        gf[1] = f1 + f3;
        gf[2] = f2 + f4;
        gf[3] = fabsf(f1 - f3);
        gf[4] = fabsf(f2 - f4);
        gf[5] = gf[1] + gf[2];
        const float avg = 0.25f * gf[5];
        const float d1 = f1 - avg, d2 = f2 - avg, d3 = f3 - avg, d4 = f4 - avg;
        gf[6] = d1 * d1 + d2 * d2 + d3 * d3 + d4 * d4;
        gf[7] = 0.0f;
        union U {
            short8 v;
            __hip_bfloat16 h[8];
        } uh;
#pragma unroll
        for (int f = 0; f < 8; ++f) uh.h[f] = f2b(gf[f]);
        *reinterpret_cast<short8*>(&Asm[bs][e_loc * ASA + ch * 8]) = uh.v;
    };
    auto loadB = [&](int cch, short8 (&bq)[2][4]) {
#pragma unroll
        for (int ks = 0; ks < 2; ++ks)
#pragma unroll
            for (int nt = 0; nt < 4; ++nt)
                bq[ks][nt] = *reinterpret_cast<const short8*>(
                    wf2 + ((((size_t)cch * 4 + w4) * 4 + nt) * 2 + ks) * 512 + lane * 8);
    };
    auto mfma_phase = [&](int bs, short8 (&bq)[2][4]) {
        __builtin_amdgcn_s_setprio(1);
#pragma unroll
        for (int ks = 0; ks < 2; ++ks) {
#pragma unroll
            for (int mt = 0; mt < 2; ++mt) {
                const int r = (wm + mt * 16 + l15) * ASA + ks * 32 + qd * 8;
                const short8 ah = *reinterpret_cast<const short8*>(&Asm[bs][r]);
#pragma unroll
                for (int nt = 0; nt < 4; ++nt)
                    acc[mt][nt] = __builtin_amdgcn_mfma_f32_16x16x32_bf16(ah, bq[ks][nt],
                                                                          acc[mt][nt], 0, 0, 0);
            }
        }
        __builtin_amdgcn_s_setprio(0);
    };

    short8 bqA[2][4], bqB[2][4];

    // ---- prologue: chunk 0 into buf 0; B(0) and chunk-1 gathers in flight
    issue_gathers(0);
    loadB(0, bqA);
    if constexpr (BN) barrier_lds();  // ssc/ssb must be visible before produce(0,0)
    produce(0, 0);
    issue_gathers(1);
    barrier_lds();  // Asm[0] visible

    // ---- main loop, 2 chunks per iteration (NCH even); bqA/bqB static ping-pong
    for (int ci0 = 0; ci0 < NCH; ci0 += 2) {
        // even chunk ci0: consume buf0 with bqA
        loadB(ci0 + 1, bqB);  // ci0+1 <= NCH-1 always
        produce(ci0 + 1, 1);
        if (ci0 + 2 < NCH) issue_gathers(ci0 + 2);
        mfma_phase(0, bqA);
        barrier_lds();  // publish buf1, retire buf0

        // odd chunk ci0+1: consume buf1 with bqB
        if (ci0 + 2 < NCH) {
            loadB(ci0 + 2, bqA);
            produce(ci0 + 2, 0);
            if (ci0 + 3 < NCH) issue_gathers(ci0 + 3);
        }
        mfma_phase(1, bqB);
        barrier_lds();  // publish buf0, retire buf1
    }

    // ---- epilogue: C/D layout col = lane&15, row = (lane>>4)*4 + reg
    const size_t orow0 = (size_t)b * E_ + e0;
#pragma unroll
    for (int mt = 0; mt < 2; ++mt) {
#pragma unroll
        for (int nt = 0; nt < 4; ++nt) {
            const int col = wn + nt * 16 + l15;
            const size_t r0 = orow0 + wm + mt * 16 + qd * 4;
#pragma unroll
            for (int r = 0; r < 4; ++r) hout[(r0 + r) * 256 + col] = Cvt<TS>::to(acc[mt][nt][r]);
        }
    }
}

// ---------------- out[b][o][e] = leaky(h + h1), fp32, transposed write ----------------
template <typename TS>
__global__ void k_final(const TS* __restrict__ h, const TS* __restrict__ h1,
                        float* __restrict__ out) {
    __shared__ float t[32][33];
    const int b = blockIdx.z, o0 = blockIdx.y * 32, e0 = blockIdx.x * 32;
    const int tx = threadIdx.x & 31, ty = threadIdx.x >> 5;
#pragma unroll
    for (int i = 0; i < 4; ++i) {
        const int e = ty + i * 8;
        const size_t idx = ((size_t)b * E_ + e0 + e) * 256 + o0 + tx;
        t[e][tx] = lk(Cvt<TS>::from(h[idx]) + Cvt<TS>::from(h1[idx]));
    }
    __syncthreads();
#pragma unroll
    for (int i = 0; i < 4; ++i) {
        const int o = ty + i * 8;
        out[((size_t)b * 256 + o0 + o) * E_ + e0 + tx] = t[tx][o];
    }
}

template <typename TS>
static void run_all(const float* x, const int* edges, const float* W0, const float* Ws,
                    const float* gammas, const float* betas, float* out, char* ws,
                    hipStream_t stream) {
    const size_t hbytes = (size_t)B_ * E_ * 256 * sizeof(TS);
    TS* h1 = (TS*)(ws);
    TS* hA = (TS*)(ws + hbytes);
    TS* hB = (TS*)(ws + 2 * hbytes);
    TS* xT = (TS*)(ws + 2 * hbytes);  // alias hB: dead before conv3 writes hB
    char* wp = ws + 3 * hbytes;
    __hip_bfloat16* wf0 = (__hip_bfloat16*)(wp);  // 512 KB (C=128)
    __hip_bfloat16* wfs[3];
    for (int i = 0; i < 3; ++i)
        wfs[i] = (__hip_bfloat16*)(wp + (512u << 10) + (size_t)i * (1u << 20));  // 1 MB each
    float* stats = (float*)(wp + (4u << 20));
    float* scale = (float*)(wp + (4u << 20) + 2048);
    float* bias = (float*)(wp + (4u << 20) + 3072);

    k_transpose_x<TS><<<dim3(E_ / 32, 4, B_), 256, 0, stream>>>(x, xT);
    k_prep_w<<<128, 256, 0, stream>>>(W0, wf0, 128);
    for (int i = 0; i < 3; ++i)
        k_prep_w<<<256, 256, 0, stream>>>(Ws + (size_t)i * 458752, wfs[i], 256);

    const dim3 gconv(1024);
    k_conv<128, false, TS><<<gconv, 512, 0, stream>>>(xT, edges, wf0, nullptr, nullptr, h1);

    TS* bin[3] = {h1, hA, hB};
    TS* bout[3] = {hA, hB, hA};
    for (int i = 0; i < 3; ++i) {
        hipMemsetAsync(stats, 0, 512 * sizeof(float), stream);
        k_bn_stats<TS><<<1024, 256, 0, stream>>>(bin[i], stats);
        k_bn_finalize<<<1, 256, 0, stream>>>(stats, gammas + 256 * i, betas + 256 * i, scale, bias);
        k_conv<256, true, TS><<<gconv, 512, 0, stream>>>(bin[i], edges, wfs[i], scale, bias,
                                                         bout[i]);
    }
    k_final<TS><<<dim3(E_ / 32, 256 / 32, B_), 256, 0, stream>>>(hA, h1, out);
}

extern "C" void kernel_launch(void* const* d_in, const int* in_sizes, int n_in, void* d_out,
                              int out_size, void* d_ws, size_t ws_size, hipStream_t stream) {
    const float* x = (const float*)d_in[0];
    const int* edges = (const int*)d_in[1];
    const float* W0 = (const float*)d_in[2];
    const float* Ws = (const float*)d_in[3];
    const float* gammas = (const float*)d_in[4];
    const float* betas = (const float*)d_in[5];
    float* out = (float*)d_out;
    char* ws = (char*)d_ws;

    // fp32-h path needs 3*64MB + ~4.1MB weights/stats; bf16-h (absmax 20 > 19.6 in r11)
    // is only the emergency fallback for small workspaces.
    if (ws_size >= 208670720ULL + 4096ULL)
        run_all<float>(x, edges, W0, Ws, gammas, betas, out, ws, stream);
    else
        run_all<__hip_bfloat16>(x, edges, W0, Ws, gammas, betas, out, ws, stream);
}

// Round 7
// 657.686 us; speedup vs baseline: 1.9976x; 1.9976x over previous
//
#include <hip/hip_runtime.h>
#include <hip/hip_bf16.h>

// MeshConvNet on MI355X (gfx950) — round 13: B-prefetch via WAR-ordered single buffer.
// r12 postmortem: bqA/bqB ping-pong + array-by-reference lambdas spilled to scratch
// (WRITE 66->713MB, FETCH 143->527MB, conv 129->316us). The double buffer was never
// needed: issuing loadB(ci+1) into the SAME bq right after mfma_phase(ci) consumes it
// gives the same load->use distance (barrier + next produce) via the WAR dependence,
// at zero extra registers. loadB/mfma_phase inlined in the loop (no array-ref lambdas).
// Everything else = r10 (absmax 12.0, conv 129us, Mfma 22): 64x256 tiles, 1 barrier/
// chunk, dbuf A in LDS, fp32 h (ws-gated), launch_bounds(512,4) = 2 blocks/CU.
// Tripwires: WRITE_SIZE ~66MB (spills), absmax == 12.0.

#define B_ 4
#define E_ 16384

typedef short short8 __attribute__((ext_vector_type(8)));
typedef float floatx4 __attribute__((ext_vector_type(4)));

__device__ __forceinline__ float lk(float v) { return v > 0.0f ? v : 0.01f * v; }
__device__ __forceinline__ float b2f(__hip_bfloat16 h) { return __bfloat162float(h); }
__device__ __forceinline__ __hip_bfloat16 f2b(float f) { return __float2bfloat16(f); }

// Barrier that only waits on LDS (lgkmcnt), not in-flight global loads (vmcnt).
__device__ __forceinline__ void barrier_lds() {
    __builtin_amdgcn_fence(__ATOMIC_RELEASE, "workgroup", "local");
    __builtin_amdgcn_s_barrier();
    __builtin_amdgcn_fence(__ATOMIC_ACQUIRE, "workgroup", "local");
}

template <typename TS>
struct Cvt;
template <>
struct Cvt<float> {
    static __device__ __forceinline__ float to(float f) { return f; }
    static __device__ __forceinline__ float from(float s) { return s; }
    static __device__ __forceinline__ float ld1(const float* p) { return *p; }
};
template <>
struct Cvt<__hip_bfloat16> {
    static __device__ __forceinline__ __hip_bfloat16 to(float f) { return f2b(f); }
    static __device__ __forceinline__ float from(__hip_bfloat16 s) { return b2f(s); }
    static __device__ __forceinline__ float ld1(const __hip_bfloat16* p) { return b2f(*p); }
};

// ---------------- x [B][128][E] fp32 -> xT [B*E][128] TS ----------------
template <typename TS>
__global__ void k_transpose_x(const float* __restrict__ x, TS* __restrict__ xT) {
    __shared__ float t[32][33];
    const int b = blockIdx.z, c0 = blockIdx.y * 32, e0 = blockIdx.x * 32;
    const int tx = threadIdx.x & 31, ty = threadIdx.x >> 5;
#pragma unroll
    for (int i = 0; i < 4; ++i) {
        const int c = ty + i * 8;
        t[c][tx] = x[((size_t)b * 128 + c0 + c) * E_ + e0 + tx];
    }
    __syncthreads();
#pragma unroll
    for (int i = 0; i < 4; ++i) {
        const int e = ty + i * 8;
        xT[((size_t)b * E_ + e0 + e) * 128 + c0 + tx] = Cvt<TS>::to(t[tx][e]);
    }
}

// ---- W [256][C][7] fp32 -> wf2 in MFMA-fragment order, bf16 hi only ----
// Layout: t = ((ci*4 + w4)*4 + nt)*2 + ks -> 64 lanes x 8 shorts (16B/lane, 1KB/wave).
// Lane (qd*16+l15) holds B[o = w4*64+nt*16+l15][k-in-chunk = (c&7)*8+f], where
// c = ci*8 + ks*4 + qd and f==7 zero-padded.
__global__ void k_prep_w(const float* __restrict__ w, __hip_bfloat16* __restrict__ wf2, int C) {
    const int NCH = C / 8;
    const int idx = blockIdx.x * blockDim.x + threadIdx.x;
    const int lane = idx & 63, t = idx >> 6;
    const int ks = t & 1, nt = (t >> 1) & 3, w4 = (t >> 3) & 3, ci = t >> 5;
    if (ci >= NCH) return;
    const int o = w4 * 64 + nt * 16 + (lane & 15);
    const int c = ci * 8 + ks * 4 + (lane >> 4);
    const float* src = w + ((size_t)o * C + c) * 7;
    __hip_bfloat16* dst = wf2 + (size_t)idx * 8;
#pragma unroll
    for (int f = 0; f < 7; ++f) dst[f] = f2b(src[f]);
    dst[7] = f2b(0.0f);
}

// ---------------- per-channel sum & sumsq of leaky(h), h [B*E][256] ----------------
template <typename TS>
__global__ void k_bn_stats(const TS* __restrict__ h, float* __restrict__ stats) {
    const int c = threadIdx.x;
    const size_t r0 = (size_t)blockIdx.x * 64;  // 1024 blocks x 64 rows
    float s = 0.0f, q = 0.0f;
    for (int r = 0; r < 64; ++r) {
        const float v = lk(Cvt<TS>::from(h[(r0 + r) * 256 + c]));
        s += v;
        q += v * v;
    }
    atomicAdd(&stats[c], s);
    atomicAdd(&stats[256 + c], q);
}

__global__ void k_bn_finalize(const float* __restrict__ stats, const float* __restrict__ gamma,
                              const float* __restrict__ beta, float* __restrict__ scale,
                              float* __restrict__ bias) {
    const int c = threadIdx.x;
    const float n = 1.0f / 65536.0f;
    const float mean = stats[c] * n;
    const float var = stats[256 + c] * n - mean * mean;
    const float inv = rsqrtf(var + 1e-5f);
    const float s = gamma[c] * inv;
    scale[c] = s;
    bias[c] = beta[c] - mean * s;
}

// ---------------- fused gather + features + bf16 MFMA GEMM ----------------
// 512 thr = 8 waves, tile 64 edges x 256 outs, chunk = 8 channels (k=64, A = bf16).
// Thread = edge (tid>>3) x channel (tid&7). A double-buffered in LDS; B fragments in a
// single bq buffer, refilled for chunk ci+1 right AFTER mfma_phase(ci) consumes them
// (WAR ordering = prefetch distance of barrier + produce, no extra regs).
// Wave tile 32x64: acc[2][4] = 32 AGPR -> 2 blocks/CU at launch_bounds(512,4).
template <int C, bool BN, typename TS>
__global__ __launch_bounds__(512, 4) void k_conv(const TS* __restrict__ hin,
                                                 const int* __restrict__ edges,
                                                 const __hip_bfloat16* __restrict__ wf2,
                                                 const float* __restrict__ scale,
                                                 const float* __restrict__ bias,
                                                 TS* __restrict__ hout) {
    constexpr int NCH = C / 8;  // chunks
    constexpr int ASA = 72;     // A row stride in shorts: [hi 64 | pad 8]
    __shared__ __align__(16) __hip_bfloat16 Asm[2][64 * ASA];  // 2 x 9216 B
    __shared__ float ssc[256];
    __shared__ float ssb[256];

    const int tid = threadIdx.x;
    const int tm = blockIdx.x;  // 1024 m-tiles (256 per batch)
    const int b = tm >> 8;
    const int e0 = (tm & 255) * 64;
    const int wave = tid >> 6, lane = tid & 63;

    if constexpr (BN) {
        if (tid < C) {
            ssc[tid] = scale[tid];
            ssb[tid] = bias[tid];
        }
    }

    // ---- gather assignment: every thread owns (edge, 1 channel)
    const int e_loc = tid >> 3;  // 0..63
    const int ch = tid & 7;      // channel within 8-ch chunk
    const TS* rp0;
    const TS* rp1;
    const TS* rp2;
    const TS* rp3;
    const TS* rp4;
    {
        const int4 nb =
            *reinterpret_cast<const int4*>(edges + (((size_t)b * E_) + e0 + e_loc) * 4);
        const size_t rb = (size_t)b * E_;
        rp0 = hin + (rb + e0 + e_loc) * C + ch;
        rp1 = hin + (rb + nb.x) * C + ch;
        rp2 = hin + (rb + nb.y) * C + ch;
        rp3 = hin + (rb + nb.z) * C + ch;
        rp4 = hin + (rb + nb.w) * C + ch;
    }

    floatx4 acc[2][4];
#pragma unroll
    for (int i = 0; i < 2; ++i)
#pragma unroll
        for (int j = 0; j < 4; ++j) {
            floatx4 z = {0.0f, 0.0f, 0.0f, 0.0f};
            acc[i][j] = z;
        }

    const int wm = (wave & 1) * 32;
    const int w4 = wave >> 1;  // 0..3: 64-col n-tile
    const int wn = w4 * 64;
    const int qd = lane >> 4, l15 = lane & 15;

    float pf[5];
    auto issue_gathers = [&](int cch) {
        const int co = cch * 8;
        pf[0] = Cvt<TS>::ld1(rp0 + co);
        pf[1] = Cvt<TS>::ld1(rp1 + co);
        pf[2] = Cvt<TS>::ld1(rp2 + co);
        pf[3] = Cvt<TS>::ld1(rp3 + co);
        pf[4] = Cvt<TS>::ld1(rp4 + co);
    };
    // pf must hold chunk cch's data; writes features into Asm[bs]
    auto produce = [&](int cch, int bs) {
        float f0 = pf[0], f1 = pf[1], f2 = pf[2], f3 = pf[3], f4 = pf[4];
        if constexpr (BN) {
            const float sA = ssc[cch * 8 + ch];
            const float bA = ssb[cch * 8 + ch];
            f0 = lk(f0) * sA + bA;
            f1 = lk(f1) * sA + bA;
            f2 = lk(f2) * sA + bA;
            f3 = lk(f3) * sA + bA;
            f4 = lk(f4) * sA + bA;
        }
        float gf[8];
        gf[0] = f0;
        gf[1] = f1 + f3;
        gf[2] = f2 + f4;
        gf[3] = fabsf(f1 - f3);
        gf[4] = fabsf(f2 - f4);
        gf[5] = gf[1] + gf[2];
        const float avg = 0.25f * gf[5];
        const float d1 = f1 - avg, d2 = f2 - avg, d3 = f3 - avg, d4 = f4 - avg;
        gf[6] = d1 * d1 + d2 * d2 + d3 * d3 + d4 * d4;
        gf[7] = 0.0f;
        union U {
            short8 v;
            __hip_bfloat16 h[8];
        } uh;
#pragma unroll
        for (int f = 0; f < 8; ++f) uh.h[f] = f2b(gf[f]);
        *reinterpret_cast<short8*>(&Asm[bs][e_loc * ASA + ch * 8]) = uh.v;
    };

    short8 bq[2][4];

    // ---- prologue: B(0) + chunk 0 gathers in flight; chunk 0 into buf 0
    issue_gathers(0);
#pragma unroll
    for (int ks = 0; ks < 2; ++ks)
#pragma unroll
        for (int nt = 0; nt < 4; ++nt)
            bq[ks][nt] = *reinterpret_cast<const short8*>(
                wf2 + ((((size_t)0 * 4 + w4) * 4 + nt) * 2 + ks) * 512 + lane * 8);
    if constexpr (BN) barrier_lds();  // ssc/ssb must be visible before produce(0,0)
    produce(0, 0);
    issue_gathers(1);
    barrier_lds();  // Asm[0] visible

    for (int ci = 0; ci < NCH; ++ci) {
        const int cur = ci & 1;

        // 1. produce chunk ci+1 into the other buffer; then refill pf for ci+2
        if (ci + 1 < NCH) {
            produce(ci + 1, cur ^ 1);
            if (ci + 2 < NCH) issue_gathers(ci + 2);
        }

        // 2. MFMA on current buffer with bq(ci) (T5: boost MFMA waves)
        __builtin_amdgcn_s_setprio(1);
#pragma unroll
        for (int ks = 0; ks < 2; ++ks) {
#pragma unroll
            for (int mt = 0; mt < 2; ++mt) {
                const int r = (wm + mt * 16 + l15) * ASA + ks * 32 + qd * 8;
                const short8 ah = *reinterpret_cast<const short8*>(&Asm[cur][r]);
#pragma unroll
                for (int nt = 0; nt < 4; ++nt)
                    acc[mt][nt] = __builtin_amdgcn_mfma_f32_16x16x32_bf16(ah, bq[ks][nt],
                                                                          acc[mt][nt], 0, 0, 0);
            }
        }
        __builtin_amdgcn_s_setprio(0);

        // 3. refill bq for chunk ci+1 — WAR on bq pins these loads after the MFMAs;
        //    they fly across the barrier and land during next iteration's produce.
        if (ci + 1 < NCH) {
#pragma unroll
            for (int ks = 0; ks < 2; ++ks)
#pragma unroll
                for (int nt = 0; nt < 4; ++nt)
                    bq[ks][nt] = *reinterpret_cast<const short8*>(
                        wf2 + ((((size_t)(ci + 1) * 4 + w4) * 4 + nt) * 2 + ks) * 512 +
                        lane * 8);
        }

        // single barrier: publishes buf[cur^1] writes, retires buf[cur] reads
        barrier_lds();
    }

    // ---- epilogue: C/D layout col = lane&15, row = (lane>>4)*4 + reg
    const size_t orow0 = (size_t)b * E_ + e0;
#pragma unroll
    for (int mt = 0; mt < 2; ++mt) {
#pragma unroll
        for (int nt = 0; nt < 4; ++nt) {
            const int col = wn + nt * 16 + l15;
            const size_t r0 = orow0 + wm + mt * 16 + qd * 4;
#pragma unroll
            for (int r = 0; r < 4; ++r) hout[(r0 + r) * 256 + col] = Cvt<TS>::to(acc[mt][nt][r]);
        }
    }
}

// ---------------- out[b][o][e] = leaky(h + h1), fp32, transposed write ----------------
template <typename TS>
__global__ void k_final(const TS* __restrict__ h, const TS* __restrict__ h1,
                        float* __restrict__ out) {
    __shared__ float t[32][33];
    const int b = blockIdx.z, o0 = blockIdx.y * 32, e0 = blockIdx.x * 32;
    const int tx = threadIdx.x & 31, ty = threadIdx.x >> 5;
#pragma unroll
    for (int i = 0; i < 4; ++i) {
        const int e = ty + i * 8;
        const size_t idx = ((size_t)b * E_ + e0 + e) * 256 + o0 + tx;
        t[e][tx] = lk(Cvt<TS>::from(h[idx]) + Cvt<TS>::from(h1[idx]));
    }
    __syncthreads();
#pragma unroll
    for (int i = 0; i < 4; ++i) {
        const int o = ty + i * 8;
        out[((size_t)b * 256 + o0 + o) * E_ + e0 + tx] = t[tx][o];
    }
}

template <typename TS>
static void run_all(const float* x, const int* edges, const float* W0, const float* Ws,
                    const float* gammas, const float* betas, float* out, char* ws,
                    hipStream_t stream) {
    const size_t hbytes = (size_t)B_ * E_ * 256 * sizeof(TS);
    TS* h1 = (TS*)(ws);
    TS* hA = (TS*)(ws + hbytes);
    TS* hB = (TS*)(ws + 2 * hbytes);
    TS* xT = (TS*)(ws + 2 * hbytes);  // alias hB: dead before conv3 writes hB
    char* wp = ws + 3 * hbytes;
    __hip_bfloat16* wf0 = (__hip_bfloat16*)(wp);  // 512 KB (C=128)
    __hip_bfloat16* wfs[3];
    for (int i = 0; i < 3; ++i)
        wfs[i] = (__hip_bfloat16*)(wp + (512u << 10) + (size_t)i * (1u << 20));  // 1 MB each
    float* stats = (float*)(wp + (4u << 20));
    float* scale = (float*)(wp + (4u << 20) + 2048);
    float* bias = (float*)(wp + (4u << 20) + 3072);

    k_transpose_x<TS><<<dim3(E_ / 32, 4, B_), 256, 0, stream>>>(x, xT);
    k_prep_w<<<128, 256, 0, stream>>>(W0, wf0, 128);
    for (int i = 0; i < 3; ++i)
        k_prep_w<<<256, 256, 0, stream>>>(Ws + (size_t)i * 458752, wfs[i], 256);

    const dim3 gconv(1024);
    k_conv<128, false, TS><<<gconv, 512, 0, stream>>>(xT, edges, wf0, nullptr, nullptr, h1);

    TS* bin[3] = {h1, hA, hB};
    TS* bout[3] = {hA, hB, hA};
    for (int i = 0; i < 3; ++i) {
        hipMemsetAsync(stats, 0, 512 * sizeof(float), stream);
        k_bn_stats<TS><<<1024, 256, 0, stream>>>(bin[i], stats);
        k_bn_finalize<<<1, 256, 0, stream>>>(stats, gammas + 256 * i, betas + 256 * i, scale, bias);
        k_conv<256, true, TS><<<gconv, 512, 0, stream>>>(bin[i], edges, wfs[i], scale, bias,
                                                         bout[i]);
    }
    k_final<TS><<<dim3(E_ / 32, 256 / 32, B_), 256, 0, stream>>>(hA, h1, out);
}

extern "C" void kernel_launch(void* const* d_in, const int* in_sizes, int n_in, void* d_out,
                              int out_size, void* d_ws, size_t ws_size, hipStream_t stream) {
    const float* x = (const float*)d_in[0];
    const int* edges = (const int*)d_in[1];
    const float* W0 = (const float*)d_in[2];
    const float* Ws = (const float*)d_in[3];
    const float* gammas = (const float*)d_in[4];
    const float* betas = (const float*)d_in[5];
    float* out = (float*)d_out;
    char* ws = (char*)d_ws;

    // fp32-h path needs 3*64MB + ~4.1MB weights/stats; bf16-h (absmax 20 > 19.6 in r11)
    // is only the emergency fallback for small workspaces.
    if (ws_size >= 208670720ULL + 4096ULL)
        run_all<float>(x, edges, W0, Ws, gammas, betas, out, ws, stream);
    else
        run_all<__hip_bfloat16>(x, edges, W0, Ws, gammas, betas, out, ws, stream);
}

// Round 8
// 604.864 us; speedup vs baseline: 2.1721x; 1.0873x over previous
//
#include <hip/hip_runtime.h>
#include <hip/hip_bf16.h>

// MeshConvNet on MI355X (gfx950) — round 14: fuse bn_stats + k_final into k_conv epilogues.
// r13 postmortem: B-prefetch was minor (129->124.5us); conv inner loop is gather-HBM-
// latency-bound (20 loads in flight/SIMD x ~900cyc ~= the ~1170cyc/chunk observed).
// Leave the loop alone; collect the ~150us of aux kernels instead:
//   (1) STATS fusion: conv1-3 accumulate per-channel sum/sumsq of lk(output) in the
//       epilogue (thread partials -> LDS atomics[256] -> 1 global atomicAdd/ch/block).
//       Deletes 3x bn_stats (3x64MB re-reads + launches). Stats order changes ~1e-7.
//   (2) FINAL fusion: conv4 epilogue computes leaky(acc+h1) and writes out[b][o][e]
//       directly (4 rows/thread = one aligned float4 store). Deletes k_final (192MB).
// Main loop frozen from r13. Tripwires: conv WRITE ~66MB, VGPR<=64, absmax ~12.

#define B_ 4
#define E_ 16384

typedef short short8 __attribute__((ext_vector_type(8)));
typedef float floatx4 __attribute__((ext_vector_type(4)));

__device__ __forceinline__ float lk(float v) { return v > 0.0f ? v : 0.01f * v; }
__device__ __forceinline__ float b2f(__hip_bfloat16 h) { return __bfloat162float(h); }
__device__ __forceinline__ __hip_bfloat16 f2b(float f) { return __float2bfloat16(f); }

// Barrier that only waits on LDS (lgkmcnt), not in-flight global loads (vmcnt).
__device__ __forceinline__ void barrier_lds() {
    __builtin_amdgcn_fence(__ATOMIC_RELEASE, "workgroup", "local");
    __builtin_amdgcn_s_barrier();
    __builtin_amdgcn_fence(__ATOMIC_ACQUIRE, "workgroup", "local");
}

template <typename TS>
struct Cvt;
template <>
struct Cvt<float> {
    static __device__ __forceinline__ float to(float f) { return f; }
    static __device__ __forceinline__ float from(float s) { return s; }
    static __device__ __forceinline__ float ld1(const float* p) { return *p; }
};
template <>
struct Cvt<__hip_bfloat16> {
    static __device__ __forceinline__ __hip_bfloat16 to(float f) { return f2b(f); }
    static __device__ __forceinline__ float from(__hip_bfloat16 s) { return b2f(s); }
    static __device__ __forceinline__ float ld1(const __hip_bfloat16* p) { return b2f(*p); }
};

// ---------------- x [B][128][E] fp32 -> xT [B*E][128] TS ----------------
template <typename TS>
__global__ void k_transpose_x(const float* __restrict__ x, TS* __restrict__ xT) {
    __shared__ float t[32][33];
    const int b = blockIdx.z, c0 = blockIdx.y * 32, e0 = blockIdx.x * 32;
    const int tx = threadIdx.x & 31, ty = threadIdx.x >> 5;
#pragma unroll
    for (int i = 0; i < 4; ++i) {
        const int c = ty + i * 8;
        t[c][tx] = x[((size_t)b * 128 + c0 + c) * E_ + e0 + tx];
    }
    __syncthreads();
#pragma unroll
    for (int i = 0; i < 4; ++i) {
        const int e = ty + i * 8;
        xT[((size_t)b * E_ + e0 + e) * 128 + c0 + tx] = Cvt<TS>::to(t[tx][e]);
    }
}

// ---- W [256][C][7] fp32 -> wf2 in MFMA-fragment order, bf16 hi only ----
// Layout: t = ((ci*4 + w4)*4 + nt)*2 + ks -> 64 lanes x 8 shorts (16B/lane, 1KB/wave).
// Lane (qd*16+l15) holds B[o = w4*64+nt*16+l15][k-in-chunk = (c&7)*8+f], where
// c = ci*8 + ks*4 + qd and f==7 zero-padded.
__global__ void k_prep_w(const float* __restrict__ w, __hip_bfloat16* __restrict__ wf2, int C) {
    const int NCH = C / 8;
    const int idx = blockIdx.x * blockDim.x + threadIdx.x;
    const int lane = idx & 63, t = idx >> 6;
    const int ks = t & 1, nt = (t >> 1) & 3, w4 = (t >> 3) & 3, ci = t >> 5;
    if (ci >= NCH) return;
    const int o = w4 * 64 + nt * 16 + (lane & 15);
    const int c = ci * 8 + ks * 4 + (lane >> 4);
    const float* src = w + ((size_t)o * C + c) * 7;
    __hip_bfloat16* dst = wf2 + (size_t)idx * 8;
#pragma unroll
    for (int f = 0; f < 7; ++f) dst[f] = f2b(src[f]);
    dst[7] = f2b(0.0f);
}

__global__ void k_bn_finalize(const float* __restrict__ stats, const float* __restrict__ gamma,
                              const float* __restrict__ beta, float* __restrict__ scale,
                              float* __restrict__ bias) {
    const int c = threadIdx.x;
    const float n = 1.0f / 65536.0f;
    const float mean = stats[c] * n;
    const float var = stats[256 + c] * n - mean * mean;
    const float inv = rsqrtf(var + 1e-5f);
    const float s = gamma[c] * inv;
    scale[c] = s;
    bias[c] = beta[c] - mean * s;
}

// ---------------- fused gather + features + bf16 MFMA GEMM ----------------
// 512 thr = 8 waves, tile 64 edges x 256 outs, chunk = 8 channels (k=64, A = bf16).
// Thread = edge (tid>>3) x channel (tid&7). A double-buffered in LDS; B fragments in a
// single bq buffer, refilled for chunk ci+1 right AFTER the MFMAs consume them (WAR
// ordering = prefetch distance of barrier + produce, no extra regs).
// Wave tile 32x64: acc[2][4] = 32 AGPR -> 2 blocks/CU at launch_bounds(512,4).
// STATS: epilogue accumulates per-channel sum/sumsq of lk(output) into stats[512].
// FINAL: epilogue writes leaky(acc + h1res) to outf[b][o][e] (transposed, float4).
template <int C, bool BN, bool STATS, bool FINAL, typename TS>
__global__ __launch_bounds__(512, 4) void k_conv(const TS* __restrict__ hin,
                                                 const int* __restrict__ edges,
                                                 const __hip_bfloat16* __restrict__ wf2,
                                                 const float* __restrict__ scale,
                                                 const float* __restrict__ bias,
                                                 TS* __restrict__ hout,
                                                 float* __restrict__ stats,
                                                 const TS* __restrict__ h1res,
                                                 float* __restrict__ outf) {
    constexpr int NCH = C / 8;  // chunks
    constexpr int ASA = 72;     // A row stride in shorts: [hi 64 | pad 8]
    __shared__ __align__(16) __hip_bfloat16 Asm[2][64 * ASA];  // 2 x 9216 B
    __shared__ float ssc[256];
    __shared__ float ssb[256];
    __shared__ float ssum[STATS ? 256 : 1];
    __shared__ float ssq[STATS ? 256 : 1];

    const int tid = threadIdx.x;
    const int tm = blockIdx.x;  // 1024 m-tiles (256 per batch)
    const int b = tm >> 8;
    const int e0 = (tm & 255) * 64;
    const int wave = tid >> 6, lane = tid & 63;

    if constexpr (BN) {
        if (tid < C) {
            ssc[tid] = scale[tid];
            ssb[tid] = bias[tid];
        }
    }
    if constexpr (STATS) {
        if (tid < 256) {
            ssum[tid] = 0.0f;
            ssq[tid] = 0.0f;
        }
    }

    // ---- gather assignment: every thread owns (edge, 1 channel)
    const int e_loc = tid >> 3;  // 0..63
    const int ch = tid & 7;      // channel within 8-ch chunk
    const TS* rp0;
    const TS* rp1;
    const TS* rp2;
    const TS* rp3;
    const TS* rp4;
    {
        const int4 nb =
            *reinterpret_cast<const int4*>(edges + (((size_t)b * E_) + e0 + e_loc) * 4);
        const size_t rb = (size_t)b * E_;
        rp0 = hin + (rb + e0 + e_loc) * C + ch;
        rp1 = hin + (rb + nb.x) * C + ch;
        rp2 = hin + (rb + nb.y) * C + ch;
        rp3 = hin + (rb + nb.z) * C + ch;
        rp4 = hin + (rb + nb.w) * C + ch;
    }

    floatx4 acc[2][4];
#pragma unroll
    for (int i = 0; i < 2; ++i)
#pragma unroll
        for (int j = 0; j < 4; ++j) {
            floatx4 z = {0.0f, 0.0f, 0.0f, 0.0f};
            acc[i][j] = z;
        }

    const int wm = (wave & 1) * 32;
    const int w4 = wave >> 1;  // 0..3: 64-col n-tile
    const int wn = w4 * 64;
    const int qd = lane >> 4, l15 = lane & 15;

    float pf[5];
    auto issue_gathers = [&](int cch) {
        const int co = cch * 8;
        pf[0] = Cvt<TS>::ld1(rp0 + co);
        pf[1] = Cvt<TS>::ld1(rp1 + co);
        pf[2] = Cvt<TS>::ld1(rp2 + co);
        pf[3] = Cvt<TS>::ld1(rp3 + co);
        pf[4] = Cvt<TS>::ld1(rp4 + co);
    };
    // pf must hold chunk cch's data; writes features into Asm[bs]
    auto produce = [&](int cch, int bs) {
        float f0 = pf[0], f1 = pf[1], f2 = pf[2], f3 = pf[3], f4 = pf[4];
        if constexpr (BN) {
            const float sA = ssc[cch * 8 + ch];
            const float bA = ssb[cch * 8 + ch];
            f0 = lk(f0) * sA + bA;
            f1 = lk(f1) * sA + bA;
            f2 = lk(f2) * sA + bA;
            f3 = lk(f3) * sA + bA;
            f4 = lk(f4) * sA + bA;
        }
        float gf[8];
        gf[0] = f0;
        gf[1] = f1 + f3;
        gf[2] = f2 + f4;
        gf[3] = fabsf(f1 - f3);
        gf[4] = fabsf(f2 - f4);
        gf[5] = gf[1] + gf[2];
        const float avg = 0.25f * gf[5];
        const float d1 = f1 - avg, d2 = f2 - avg, d3 = f3 - avg, d4 = f4 - avg;
        gf[6] = d1 * d1 + d2 * d2 + d3 * d3 + d4 * d4;
        gf[7] = 0.0f;
        union U {
            short8 v;
            __hip_bfloat16 h[8];
        } uh;
#pragma unroll
        for (int f = 0; f < 8; ++f) uh.h[f] = f2b(gf[f]);
        *reinterpret_cast<short8*>(&Asm[bs][e_loc * ASA + ch * 8]) = uh.v;
    };

    short8 bq[2][4];

    // ---- prologue: B(0) + chunk 0 gathers in flight; chunk 0 into buf 0
    issue_gathers(0);
#pragma unroll
    for (int ks = 0; ks < 2; ++ks)
#pragma unroll
        for (int nt = 0; nt < 4; ++nt)
            bq[ks][nt] = *reinterpret_cast<const short8*>(
                wf2 + ((((size_t)0 * 4 + w4) * 4 + nt) * 2 + ks) * 512 + lane * 8);
    if constexpr (BN) barrier_lds();  // ssc/ssb must be visible before produce(0,0)
    produce(0, 0);
    issue_gathers(1);
    barrier_lds();  // Asm[0] visible

    for (int ci = 0; ci < NCH; ++ci) {
        const int cur = ci & 1;

        // 1. produce chunk ci+1 into the other buffer; then refill pf for ci+2
        if (ci + 1 < NCH) {
            produce(ci + 1, cur ^ 1);
            if (ci + 2 < NCH) issue_gathers(ci + 2);
        }

        // 2. MFMA on current buffer with bq(ci) (T5: boost MFMA waves)
        __builtin_amdgcn_s_setprio(1);
#pragma unroll
        for (int ks = 0; ks < 2; ++ks) {
#pragma unroll
            for (int mt = 0; mt < 2; ++mt) {
                const int r = (wm + mt * 16 + l15) * ASA + ks * 32 + qd * 8;
                const short8 ah = *reinterpret_cast<const short8*>(&Asm[cur][r]);
#pragma unroll
                for (int nt = 0; nt < 4; ++nt)
                    acc[mt][nt] = __builtin_amdgcn_mfma_f32_16x16x32_bf16(ah, bq[ks][nt],
                                                                          acc[mt][nt], 0, 0, 0);
            }
        }
        __builtin_amdgcn_s_setprio(0);

        // 3. refill bq for chunk ci+1 — WAR on bq pins these loads after the MFMAs;
        //    they fly across the barrier and land during next iteration's produce.
        if (ci + 1 < NCH) {
#pragma unroll
            for (int ks = 0; ks < 2; ++ks)
#pragma unroll
                for (int nt = 0; nt < 4; ++nt)
                    bq[ks][nt] = *reinterpret_cast<const short8*>(
                        wf2 + ((((size_t)(ci + 1) * 4 + w4) * 4 + nt) * 2 + ks) * 512 +
                        lane * 8);
        }

        // single barrier: publishes buf[cur^1] writes, retires buf[cur] reads
        barrier_lds();
    }

    // ---- epilogue: C/D layout col = lane&15, row = (lane>>4)*4 + reg
    const size_t orow0 = (size_t)b * E_ + e0;
    float snt[4], qnt[4];
    if constexpr (STATS) {
#pragma unroll
        for (int nt = 0; nt < 4; ++nt) {
            snt[nt] = 0.0f;
            qnt[nt] = 0.0f;
        }
    }
#pragma unroll
    for (int mt = 0; mt < 2; ++mt) {
#pragma unroll
        for (int nt = 0; nt < 4; ++nt) {
            const int col = wn + nt * 16 + l15;
            const size_t r0 = orow0 + wm + mt * 16 + qd * 4;
            if constexpr (FINAL) {
                float4 o4;
                o4.x = lk(acc[mt][nt][0] + Cvt<TS>::from(h1res[(r0 + 0) * 256 + col]));
                o4.y = lk(acc[mt][nt][1] + Cvt<TS>::from(h1res[(r0 + 1) * 256 + col]));
                o4.z = lk(acc[mt][nt][2] + Cvt<TS>::from(h1res[(r0 + 2) * 256 + col]));
                o4.w = lk(acc[mt][nt][3] + Cvt<TS>::from(h1res[(r0 + 3) * 256 + col]));
                const int erow = e0 + wm + mt * 16 + qd * 4;
                *reinterpret_cast<float4*>(&outf[((size_t)b * 256 + col) * E_ + erow]) = o4;
            } else {
#pragma unroll
                for (int r = 0; r < 4; ++r) {
                    const float v = acc[mt][nt][r];
                    hout[(r0 + r) * 256 + col] = Cvt<TS>::to(v);
                    if constexpr (STATS) {
                        const float lv = lk(v);
                        snt[nt] += lv;
                        qnt[nt] += lv * lv;
                    }
                }
            }
        }
    }
    if constexpr (STATS) {
#pragma unroll
        for (int nt = 0; nt < 4; ++nt) {
            atomicAdd(&ssum[wn + nt * 16 + l15], snt[nt]);
            atomicAdd(&ssq[wn + nt * 16 + l15], qnt[nt]);
        }
        __syncthreads();
        if (tid < 256) {
            atomicAdd(&stats[tid], ssum[tid]);
            atomicAdd(&stats[256 + tid], ssq[tid]);
        }
    }
}

template <typename TS>
static void run_all(const float* x, const int* edges, const float* W0, const float* Ws,
                    const float* gammas, const float* betas, float* out, char* ws,
                    hipStream_t stream) {
    const size_t hbytes = (size_t)B_ * E_ * 256 * sizeof(TS);
    TS* h1 = (TS*)(ws);
    TS* hA = (TS*)(ws + hbytes);
    TS* hB = (TS*)(ws + 2 * hbytes);
    TS* xT = (TS*)(ws + 2 * hbytes);  // alias hB: dead before conv3 writes hB
    char* wp = ws + 3 * hbytes;
    __hip_bfloat16* wf0 = (__hip_bfloat16*)(wp);  // 512 KB (C=128)
    __hip_bfloat16* wfs[3];
    for (int i = 0; i < 3; ++i)
        wfs[i] = (__hip_bfloat16*)(wp + (512u << 10) + (size_t)i * (1u << 20));  // 1 MB each
    float* stats = (float*)(wp + (4u << 20));  // 3 x 512 floats
    float* scale = (float*)(wp + (4u << 20) + 8192);
    float* bias = (float*)(wp + (4u << 20) + 9216);

    hipMemsetAsync(stats, 0, 3 * 512 * sizeof(float), stream);
    k_transpose_x<TS><<<dim3(E_ / 32, 4, B_), 256, 0, stream>>>(x, xT);
    k_prep_w<<<128, 256, 0, stream>>>(W0, wf0, 128);
    for (int i = 0; i < 3; ++i)
        k_prep_w<<<256, 256, 0, stream>>>(Ws + (size_t)i * 458752, wfs[i], 256);

    const dim3 gconv(1024);
    // conv1: STATS for BN of skip-0
    k_conv<128, false, true, false, TS><<<gconv, 512, 0, stream>>>(
        xT, edges, wf0, nullptr, nullptr, h1, stats, nullptr, nullptr);

    TS* bin[3] = {h1, hA, hB};
    TS* bout[3] = {hA, hB, nullptr};
    for (int i = 0; i < 3; ++i) {
        k_bn_finalize<<<1, 256, 0, stream>>>(stats + 512 * i, gammas + 256 * i, betas + 256 * i,
                                             scale, bias);
        if (i < 2) {
            // conv2/3: BN + STATS for the next skip's BN
            k_conv<256, true, true, false, TS><<<gconv, 512, 0, stream>>>(
                bin[i], edges, wfs[i], scale, bias, bout[i], stats + 512 * (i + 1), nullptr,
                nullptr);
        } else {
            // conv4: BN + FINAL (leaky(acc + h1) -> out[b][o][e])
            k_conv<256, true, false, true, TS><<<gconv, 512, 0, stream>>>(
                bin[i], edges, wfs[i], scale, bias, nullptr, nullptr, h1, out);
        }
    }
}

extern "C" void kernel_launch(void* const* d_in, const int* in_sizes, int n_in, void* d_out,
                              int out_size, void* d_ws, size_t ws_size, hipStream_t stream) {
    const float* x = (const float*)d_in[0];
    const int* edges = (const int*)d_in[1];
    const float* W0 = (const float*)d_in[2];
    const float* Ws = (const float*)d_in[3];
    const float* gammas = (const float*)d_in[4];
    const float* betas = (const float*)d_in[5];
    float* out = (float*)d_out;
    char* ws = (char*)d_ws;

    // fp32-h path needs 3*64MB + ~4.1MB weights/stats; bf16-h (absmax 20 > 19.6 in r11)
    // is only the emergency fallback for small workspaces.
    if (ws_size >= 208670720ULL + 4096ULL)
        run_all<float>(x, edges, W0, Ws, gammas, betas, out, ws, stream);
    else
        run_all<__hip_bfloat16>(x, edges, W0, Ws, gammas, betas, out, ws, stream);
}

// Round 10
// 509.408 us; speedup vs baseline: 2.5791x; 1.1874x over previous
//
#include <hip/hip_runtime.h>
#include <hip/hip_bf16.h>

// MeshConvNet on MI355X (gfx950) — round 16: resubmit r15 (infra failure, never ran).
// r15 theory unchanged: K=128 LDS stages (halve barriers) + cheap stats.
// r14 postmortem: fusion net-won (605us) but each fused conv rose 124.5->150: stats LDS
// atomics (4096/block, 8-way contention) + h1 reads + the unchanged 1-barrier-per-chunk
// lockstep (~55% no-issue cycles, 32 barriers x slowest-wave skew). This round:
//   (1) Stage = 2 chunks (K=128): MFMA kq01 -> WAR-refill bq(kq23) -> produce 2ch
//       (covers refill) -> MFMA kq23 -> refill bq(next) -> ONE barrier. 16 vs 32
//       barriers; 10-deep gather bursts; single bq (no r12 reg blowup). MFMA order
//       preserved exactly -> bit-identical conv output.
//   (2) STATS epilogue: shfl_xor(16/32) qd-reduce first -> LDS atomics 4096->1024,
//       contention 8->2-way. Stats order changes ~1e-7 (invisible at bf16 scale).
// Tripwires: VGPR ~64, WRITE ~66-68MB (spills), absmax ~12.

#define B_ 4
#define E_ 16384

typedef short short8 __attribute__((ext_vector_type(8)));
typedef float floatx4 __attribute__((ext_vector_type(4)));

__device__ __forceinline__ float lk(float v) { return v > 0.0f ? v : 0.01f * v; }
__device__ __forceinline__ float b2f(__hip_bfloat16 h) { return __bfloat162float(h); }
__device__ __forceinline__ __hip_bfloat16 f2b(float f) { return __float2bfloat16(f); }

// Barrier that only waits on LDS (lgkmcnt), not in-flight global loads (vmcnt).
__device__ __forceinline__ void barrier_lds() {
    __builtin_amdgcn_fence(__ATOMIC_RELEASE, "workgroup", "local");
    __builtin_amdgcn_s_barrier();
    __builtin_amdgcn_fence(__ATOMIC_ACQUIRE, "workgroup", "local");
}

template <typename TS>
struct Cvt;
template <>
struct Cvt<float> {
    static __device__ __forceinline__ float to(float f) { return f; }
    static __device__ __forceinline__ float from(float s) { return s; }
    static __device__ __forceinline__ float ld1(const float* p) { return *p; }
};
template <>
struct Cvt<__hip_bfloat16> {
    static __device__ __forceinline__ __hip_bfloat16 to(float f) { return f2b(f); }
    static __device__ __forceinline__ float from(__hip_bfloat16 s) { return b2f(s); }
    static __device__ __forceinline__ float ld1(const __hip_bfloat16* p) { return b2f(*p); }
};

// ---------------- x [B][128][E] fp32 -> xT [B*E][128] TS ----------------
template <typename TS>
__global__ void k_transpose_x(const float* __restrict__ x, TS* __restrict__ xT) {
    __shared__ float t[32][33];
    const int b = blockIdx.z, c0 = blockIdx.y * 32, e0 = blockIdx.x * 32;
    const int tx = threadIdx.x & 31, ty = threadIdx.x >> 5;
#pragma unroll
    for (int i = 0; i < 4; ++i) {
        const int c = ty + i * 8;
        t[c][tx] = x[((size_t)b * 128 + c0 + c) * E_ + e0 + tx];
    }
    __syncthreads();
#pragma unroll
    for (int i = 0; i < 4; ++i) {
        const int e = ty + i * 8;
        xT[((size_t)b * E_ + e0 + e) * 128 + c0 + tx] = Cvt<TS>::to(t[tx][e]);
    }
}

// ---- W [256][C][7] fp32 -> wf2 in MFMA-fragment order, bf16 hi only ----
// Layout: t = ((ci*4 + w4)*4 + nt)*2 + ks -> 64 lanes x 8 shorts (16B/lane, 1KB/wave).
// Lane (qd*16+l15) holds B[o = w4*64+nt*16+l15][k-in-chunk = (c&7)*8+f], where
// c = ci*8 + ks*4 + qd and f==7 zero-padded.
__global__ void k_prep_w(const float* __restrict__ w, __hip_bfloat16* __restrict__ wf2, int C) {
    const int NCH = C / 8;
    const int idx = blockIdx.x * blockDim.x + threadIdx.x;
    const int lane = idx & 63, t = idx >> 6;
    const int ks = t & 1, nt = (t >> 1) & 3, w4 = (t >> 3) & 3, ci = t >> 5;
    if (ci >= NCH) return;
    const int o = w4 * 64 + nt * 16 + (lane & 15);
    const int c = ci * 8 + ks * 4 + (lane >> 4);
    const float* src = w + ((size_t)o * C + c) * 7;
    __hip_bfloat16* dst = wf2 + (size_t)idx * 8;
#pragma unroll
    for (int f = 0; f < 7; ++f) dst[f] = f2b(src[f]);
    dst[7] = f2b(0.0f);
}

__global__ void k_bn_finalize(const float* __restrict__ stats, const float* __restrict__ gamma,
                              const float* __restrict__ beta, float* __restrict__ scale,
                              float* __restrict__ bias) {
    const int c = threadIdx.x;
    const float n = 1.0f / 65536.0f;
    const float mean = stats[c] * n;
    const float var = stats[256 + c] * n - mean * mean;
    const float inv = rsqrtf(var + 1e-5f);
    const float s = gamma[c] * inv;
    scale[c] = s;
    bias[c] = beta[c] - mean * s;
}

// ---------------- fused gather + features + bf16 MFMA GEMM ----------------
// 512 thr = 8 waves, tile 64 edges x 256 outs, STAGE = 16 channels (K=128, A = bf16).
// Thread = edge (tid>>3) x channel (tid&7, handles ch and ch+8 of each stage).
// A double-buffered in LDS (2 x 17.4KB); one barrier per STAGE (2 chunks).
// B frags (single bq[2][4]) refilled twice per stage, WAR-ordered with cover phases.
// Wave tile 32x64: acc[2][4] = 32 AGPR -> 2 blocks/CU at launch_bounds(512,4).
// STATS: qd-shuffle-reduced per-channel sum/sumsq of lk(output) -> stats[512].
// FINAL: epilogue writes leaky(acc + h1res) to outf[b][o][e] (transposed, float4).
template <int C, bool BN, bool STATS, bool FINAL, typename TS>
__global__ __launch_bounds__(512, 4) void k_conv(const TS* __restrict__ hin,
                                                 const int* __restrict__ edges,
                                                 const __hip_bfloat16* __restrict__ wf2,
                                                 const float* __restrict__ scale,
                                                 const float* __restrict__ bias,
                                                 TS* __restrict__ hout,
                                                 float* __restrict__ stats,
                                                 const TS* __restrict__ h1res,
                                                 float* __restrict__ outf) {
    constexpr int NST = C / 16;  // stages (8 or 16)
    constexpr int ASA = 136;     // A row stride in shorts: [128 k-slots | pad 8]
    __shared__ __align__(16) __hip_bfloat16 Asm[2][64 * ASA];  // 2 x 17408 B
    __shared__ float ssc[256];
    __shared__ float ssb[256];
    __shared__ float ssum[STATS ? 256 : 1];
    __shared__ float ssq[STATS ? 256 : 1];

    const int tid = threadIdx.x;
    const int tm = blockIdx.x;  // 1024 m-tiles (256 per batch)
    const int b = tm >> 8;
    const int e0 = (tm & 255) * 64;
    const int wave = tid >> 6, lane = tid & 63;

    if constexpr (BN) {
        if (tid < C) {
            ssc[tid] = scale[tid];
            ssb[tid] = bias[tid];
        }
    }
    if constexpr (STATS) {
        if (tid < 256) {
            ssum[tid] = 0.0f;
            ssq[tid] = 0.0f;
        }
    }

    // ---- gather assignment: every thread owns (edge, channels ch & ch+8 per stage)
    const int e_loc = tid >> 3;  // 0..63
    const int ch = tid & 7;
    const TS* rp0;
    const TS* rp1;
    const TS* rp2;
    const TS* rp3;
    const TS* rp4;
    {
        const int4 nb =
            *reinterpret_cast<const int4*>(edges + (((size_t)b * E_) + e0 + e_loc) * 4);
        const size_t rb = (size_t)b * E_;
        rp0 = hin + (rb + e0 + e_loc) * C + ch;
        rp1 = hin + (rb + nb.x) * C + ch;
        rp2 = hin + (rb + nb.y) * C + ch;
        rp3 = hin + (rb + nb.z) * C + ch;
        rp4 = hin + (rb + nb.w) * C + ch;
    }

    floatx4 acc[2][4];
#pragma unroll
    for (int i = 0; i < 2; ++i)
#pragma unroll
        for (int j = 0; j < 4; ++j) {
            floatx4 z = {0.0f, 0.0f, 0.0f, 0.0f};
            acc[i][j] = z;
        }

    const int wm = (wave & 1) * 32;
    const int w4 = wave >> 1;  // 0..3: 64-col n-tile
    const int wn = w4 * 64;
    const int qd = lane >> 4, l15 = lane & 15;

    float pf[5][2];
    auto issue_gathers = [&](int ss) {
        const int co = ss * 16;
        pf[0][0] = Cvt<TS>::ld1(rp0 + co);
        pf[1][0] = Cvt<TS>::ld1(rp1 + co);
        pf[2][0] = Cvt<TS>::ld1(rp2 + co);
        pf[3][0] = Cvt<TS>::ld1(rp3 + co);
        pf[4][0] = Cvt<TS>::ld1(rp4 + co);
        pf[0][1] = Cvt<TS>::ld1(rp0 + co + 8);
        pf[1][1] = Cvt<TS>::ld1(rp1 + co + 8);
        pf[2][1] = Cvt<TS>::ld1(rp2 + co + 8);
        pf[3][1] = Cvt<TS>::ld1(rp3 + co + 8);
        pf[4][1] = Cvt<TS>::ld1(rp4 + co + 8);
    };
    // pf must hold stage ss's data; writes features into Asm[bs] (both channels)
    auto produce = [&](int ss, int bs) {
#pragma unroll
        for (int s2 = 0; s2 < 2; ++s2) {
            float f0 = pf[0][s2], f1 = pf[1][s2], f2 = pf[2][s2], f3 = pf[3][s2],
                  f4 = pf[4][s2];
            if constexpr (BN) {
                const float sA = ssc[ss * 16 + s2 * 8 + ch];
                const float bA = ssb[ss * 16 + s2 * 8 + ch];
                f0 = lk(f0) * sA + bA;
                f1 = lk(f1) * sA + bA;
                f2 = lk(f2) * sA + bA;
                f3 = lk(f3) * sA + bA;
                f4 = lk(f4) * sA + bA;
            }
            float gf[8];
            gf[0] = f0;
            gf[1] = f1 + f3;
            gf[2] = f2 + f4;
            gf[3] = fabsf(f1 - f3);
            gf[4] = fabsf(f2 - f4);
            gf[5] = gf[1] + gf[2];
            const float avg = 0.25f * gf[5];
            const float d1 = f1 - avg, d2 = f2 - avg, d3 = f3 - avg, d4 = f4 - avg;
            gf[6] = d1 * d1 + d2 * d2 + d3 * d3 + d4 * d4;
            gf[7] = 0.0f;
            union U {
                short8 v;
                __hip_bfloat16 h[8];
            } uh;
#pragma unroll
            for (int f = 0; f < 8; ++f) uh.h[f] = f2b(gf[f]);
            *reinterpret_cast<short8*>(&Asm[bs][e_loc * ASA + (s2 * 8 + ch) * 8]) = uh.v;
        }
    };

    short8 bq[2][4];

    // ---- prologue: gathers(0) + B(stage0, kq01) in flight; stage 0 into buf 0
    issue_gathers(0);
#pragma unroll
    for (int ks = 0; ks < 2; ++ks)
#pragma unroll
        for (int nt = 0; nt < 4; ++nt)
            bq[ks][nt] = *reinterpret_cast<const short8*>(
                wf2 + ((((size_t)0 * 4 + w4) * 4 + nt) * 2 + ks) * 512 + lane * 8);
    if constexpr (BN) barrier_lds();  // ssc/ssb must be visible before produce(0,0)
    produce(0, 0);
    issue_gathers(1);
    barrier_lds();  // Asm[0] visible

    for (int ss = 0; ss < NST; ++ss) {
        const int cur = ss & 1;

        // 1. MFMA kq0,1 (chunk 2ss) on Asm[cur] with bq
        __builtin_amdgcn_s_setprio(1);
#pragma unroll
        for (int ks = 0; ks < 2; ++ks) {
#pragma unroll
            for (int mt = 0; mt < 2; ++mt) {
                const int r = (wm + mt * 16 + l15) * ASA + ks * 32 + qd * 8;
                const short8 ah = *reinterpret_cast<const short8*>(&Asm[cur][r]);
#pragma unroll
                for (int nt = 0; nt < 4; ++nt)
                    acc[mt][nt] = __builtin_amdgcn_mfma_f32_16x16x32_bf16(ah, bq[ks][nt],
                                                                          acc[mt][nt], 0, 0, 0);
            }
        }
        __builtin_amdgcn_s_setprio(0);

        // 2. WAR-refill bq <- this stage's kq2,3 (chunk 2ss+1); covered by produce below
        {
            const size_t ci = 2 * (size_t)ss + 1;
#pragma unroll
            for (int ks = 0; ks < 2; ++ks)
#pragma unroll
                for (int nt = 0; nt < 4; ++nt)
                    bq[ks][nt] = *reinterpret_cast<const short8*>(
                        wf2 + (((ci * 4 + w4) * 4 + nt) * 2 + ks) * 512 + lane * 8);
        }

        // 3. produce stage ss+1 into the other buffer (covers the refill)
        if (ss + 1 < NST) produce(ss + 1, cur ^ 1);

        // 4. MFMA kq2,3 (chunk 2ss+1) on Asm[cur]
        __builtin_amdgcn_s_setprio(1);
#pragma unroll
        for (int ks = 0; ks < 2; ++ks) {
#pragma unroll
            for (int mt = 0; mt < 2; ++mt) {
                const int r = (wm + mt * 16 + l15) * ASA + (ks + 2) * 32 + qd * 8;
                const short8 ah = *reinterpret_cast<const short8*>(&Asm[cur][r]);
#pragma unroll
                for (int nt = 0; nt < 4; ++nt)
                    acc[mt][nt] = __builtin_amdgcn_mfma_f32_16x16x32_bf16(ah, bq[ks][nt],
                                                                          acc[mt][nt], 0, 0, 0);
            }
        }
        __builtin_amdgcn_s_setprio(0);

        // 5. WAR-refill bq <- next stage's kq0,1; then issue next gathers
        if (ss + 1 < NST) {
            const size_t ci = 2 * (size_t)(ss + 1);
#pragma unroll
            for (int ks = 0; ks < 2; ++ks)
#pragma unroll
                for (int nt = 0; nt < 4; ++nt)
                    bq[ks][nt] = *reinterpret_cast<const short8*>(
                        wf2 + (((ci * 4 + w4) * 4 + nt) * 2 + ks) * 512 + lane * 8);
            if (ss + 2 < NST) issue_gathers(ss + 2);
        }

        // single barrier per STAGE: publishes buf[cur^1], retires buf[cur]
        barrier_lds();
    }

    // ---- epilogue: C/D layout col = lane&15, row = (lane>>4)*4 + reg
    const size_t orow0 = (size_t)b * E_ + e0;
    float snt[4], qnt[4];
    if constexpr (STATS) {
#pragma unroll
        for (int nt = 0; nt < 4; ++nt) {
            snt[nt] = 0.0f;
            qnt[nt] = 0.0f;
        }
    }
#pragma unroll
    for (int mt = 0; mt < 2; ++mt) {
#pragma unroll
        for (int nt = 0; nt < 4; ++nt) {
            const int col = wn + nt * 16 + l15;
            const size_t r0 = orow0 + wm + mt * 16 + qd * 4;
            if constexpr (FINAL) {
                float4 o4;
                o4.x = lk(acc[mt][nt][0] + Cvt<TS>::from(h1res[(r0 + 0) * 256 + col]));
                o4.y = lk(acc[mt][nt][1] + Cvt<TS>::from(h1res[(r0 + 1) * 256 + col]));
                o4.z = lk(acc[mt][nt][2] + Cvt<TS>::from(h1res[(r0 + 2) * 256 + col]));
                o4.w = lk(acc[mt][nt][3] + Cvt<TS>::from(h1res[(r0 + 3) * 256 + col]));
                const int erow = e0 + wm + mt * 16 + qd * 4;
                *reinterpret_cast<float4*>(&outf[((size_t)b * 256 + col) * E_ + erow]) = o4;
            } else {
#pragma unroll
                for (int r = 0; r < 4; ++r) {
                    const float v = acc[mt][nt][r];
                    hout[(r0 + r) * 256 + col] = Cvt<TS>::to(v);
                    if constexpr (STATS) {
                        const float lv = lk(v);
                        snt[nt] += lv;
                        qnt[nt] += lv * lv;
                    }
                }
            }
        }
    }
    if constexpr (STATS) {
#pragma unroll
        for (int nt = 0; nt < 4; ++nt) {
            float s = snt[nt], q = qnt[nt];
            s += __shfl_xor(s, 16);
            q += __shfl_xor(q, 16);
            s += __shfl_xor(s, 32);
            q += __shfl_xor(q, 32);
            if (qd == 0) {
                atomicAdd(&ssum[wn + nt * 16 + l15], s);
                atomicAdd(&ssq[wn + nt * 16 + l15], q);
            }
        }
        __syncthreads();
        if (tid < 256) {
            atomicAdd(&stats[tid], ssum[tid]);
            atomicAdd(&stats[256 + tid], ssq[tid]);
        }
    }
}

template <typename TS>
static void run_all(const float* x, const int* edges, const float* W0, const float* Ws,
                    const float* gammas, const float* betas, float* out, char* ws,
                    hipStream_t stream) {
    const size_t hbytes = (size_t)B_ * E_ * 256 * sizeof(TS);
    TS* h1 = (TS*)(ws);
    TS* hA = (TS*)(ws + hbytes);
    TS* hB = (TS*)(ws + 2 * hbytes);
    TS* xT = (TS*)(ws + 2 * hbytes);  // alias hB: dead before conv3 writes hB
    char* wp = ws + 3 * hbytes;
    __hip_bfloat16* wf0 = (__hip_bfloat16*)(wp);  // 512 KB (C=128)
    __hip_bfloat16* wfs[3];
    for (int i = 0; i < 3; ++i)
        wfs[i] = (__hip_bfloat16*)(wp + (512u << 10) + (size_t)i * (1u << 20));  // 1 MB each
    float* stats = (float*)(wp + (4u << 20));  // 3 x 512 floats
    float* scale = (float*)(wp + (4u << 20) + 8192);
    float* bias = (float*)(wp + (4u << 20) + 9216);

    hipMemsetAsync(stats, 0, 3 * 512 * sizeof(float), stream);
    k_transpose_x<TS><<<dim3(E_ / 32, 4, B_), 256, 0, stream>>>(x, xT);
    k_prep_w<<<128, 256, 0, stream>>>(W0, wf0, 128);
    for (int i = 0; i < 3; ++i)
        k_prep_w<<<256, 256, 0, stream>>>(Ws + (size_t)i * 458752, wfs[i], 256);

    const dim3 gconv(1024);
    // conv1: STATS for BN of skip-0
    k_conv<128, false, true, false, TS><<<gconv, 512, 0, stream>>>(
        xT, edges, wf0, nullptr, nullptr, h1, stats, nullptr, nullptr);

    TS* bin[3] = {h1, hA, hB};
    TS* bout[3] = {hA, hB, nullptr};
    for (int i = 0; i < 3; ++i) {
        k_bn_finalize<<<1, 256, 0, stream>>>(stats + 512 * i, gammas + 256 * i, betas + 256 * i,
                                             scale, bias);
        if (i < 2) {
            // conv2/3: BN + STATS for the next skip's BN
            k_conv<256, true, true, false, TS><<<gconv, 512, 0, stream>>>(
                bin[i], edges, wfs[i], scale, bias, bout[i], stats + 512 * (i + 1), nullptr,
                nullptr);
        } else {
            // conv4: BN + FINAL (leaky(acc + h1) -> out[b][o][e])
            k_conv<256, true, false, true, TS><<<gconv, 512, 0, stream>>>(
                bin[i], edges, wfs[i], scale, bias, nullptr, nullptr, h1, out);
        }
    }
}

extern "C" void kernel_launch(void* const* d_in, const int* in_sizes, int n_in, void* d_out,
                              int out_size, void* d_ws, size_t ws_size, hipStream_t stream) {
    const float* x = (const float*)d_in[0];
    const int* edges = (const int*)d_in[1];
    const float* W0 = (const float*)d_in[2];
    const float* Ws = (const float*)d_in[3];
    const float* gammas = (const float*)d_in[4];
    const float* betas = (const float*)d_in[5];
    float* out = (float*)d_out;
    char* ws = (char*)d_ws;

    // fp32-h path needs 3*64MB + ~4.1MB weights/stats; bf16-h (absmax 20 > 19.6 in r11)
    // is only the emergency fallback for small workspaces.
    if (ws_size >= 208670720ULL + 4096ULL)
        run_all<float>(x, edges, W0, Ws, gammas, betas, out, ws, stream);
    else
        run_all<__hip_bfloat16>(x, edges, W0, Ws, gammas, betas, out, ws, stream);
}